// Round 6
// baseline (196.924 us; speedup 1.0000x reference)
//
#include <hip/hip_runtime.h>
#include <hip/hip_bf16.h>
#include <stdint.h>
#include <stddef.h>

// DecoderAttention: B=2,T=2048,C=1024,H=16,D=64, causal, p=0.0
// R6: flash critical path attack. R5 analysis: wall = longest block's serial
//     chain (32 iters x ~3300 cyc), all pipes <30%. Fix:
//     (1) double-buffered K/V LDS + ONE barrier per iter (loads for tile k+1
//         issued right after the barrier, land during compute of tile k);
//     (2) split-KV 2-way by parity — no-max softmax partials are additive:
//         fp32 atomicAdd into O/l accumulators (zeroed by convert), small
//         normalize kernel emits bf16 Ao. Max 16 iters/block, grid 2048.

typedef __bf16 bf16;
typedef __attribute__((ext_vector_type(8))) __bf16 bf16x8;
typedef __attribute__((ext_vector_type(4))) __bf16 bf16x4;
typedef __attribute__((ext_vector_type(4))) float floatx4;

#define MFMA_16x16x32(A, B, C) __builtin_amdgcn_mfma_f32_16x16x32_bf16(A, B, C, 0, 0, 0)

static constexpr int T_SEQ = 2048;
static constexpr int CDIM  = 1024;

// async 16B global->LDS. LDS dest MUST be wave-uniform-base + lane*16.
__device__ __forceinline__ void gl2lds16(const bf16* g, bf16* l) {
  __builtin_amdgcn_global_load_lds(
      (const __attribute__((address_space(1))) uint32_t*)g,
      (__attribute__((address_space(3))) uint32_t*)l, 16, 0, 0);
}

// ---------------------------------------------------------------------------
// fp32 -> bf16 conversion / packing + zeroing of flash accumulators.
__global__ __launch_bounds__(256) void convert_kernel(
    const float* __restrict__ x, const float* __restrict__ Wq,
    const float* __restrict__ Wk, const float* __restrict__ Wv,
    const float* __restrict__ Wo,
    bf16* __restrict__ Xb, bf16* __restrict__ Wqkvb, bf16* __restrict__ Wob,
    float* __restrict__ Oacc, float* __restrict__ Lacc) {
  size_t i = ((size_t)blockIdx.x * 256 + threadIdx.x) * 4;
  if (i >= 8388608) {  // zero accumulators: Oacc 4194304 floats, Lacc 65536
    size_t r = i - 8388608;
    float4 z = make_float4(0.f, 0.f, 0.f, 0.f);
    if (r < 4194304) *(float4*)(Oacc + r) = z;
    else             *(float4*)(Lacc + (r - 4194304)) = z;
    return;
  }
  const float* src;
  bf16* dst;
  size_t off;
  if (i < 4194304) {
    src = x; dst = Xb; off = i;
  } else {
    size_t r = i - 4194304;
    int wsel = (int)(r >> 20);
    off = r & 1048575;
    src = (wsel == 0) ? Wq : (wsel == 1) ? Wk : (wsel == 2) ? Wv : Wo;
    dst = (wsel < 3) ? (Wqkvb + ((size_t)wsel << 20)) : Wob;
  }
  float4 v = *(const float4*)(src + off);
  bf16x4 o;
  o[0] = (bf16)v.x; o[1] = (bf16)v.y; o[2] = (bf16)v.z; o[3] = (bf16)v.w;
  *(bf16x4*)(dst + off) = o;
}

// ---------------------------------------------------------------------------
// Kernel 2: fused QKV projection, 64x128 tiles, coalesced epilogue via LDS.
// Q pre-scaled by (1/8)*log2(e); V stored transposed [B,H,D,T].
__global__ __launch_bounds__(256) void gemm_qkv(
    const bf16* __restrict__ Xb, const bf16* __restrict__ Wqkvb,
    const float* __restrict__ bq, const float* __restrict__ bk,
    const float* __restrict__ bv,
    bf16* __restrict__ Qb, bf16* __restrict__ Kb, bf16* __restrict__ Vtb) {
  __shared__ __align__(16) bf16 smem[12288];  // 24 KB: As(4096)+Bs(8192) / Cs
  bf16* As = smem;          // 64 x 64
  bf16* Bs = smem + 4096;   // 128 x 64
  bf16* Cs = smem;          // overlay after final barrier

  const int bM = blockIdx.x & 63;   // 64 M-tiles of 64 rows (4096)
  const int bN = blockIdx.x >> 6;   // 24 N-tiles of 128 cols (3072)
  const int tid = threadIdx.x;
  const int w = tid >> 6, l = tid & 63;
  const int wm = w & 1, wn = w >> 1;   // wave tile: 32 rows x 64 cols
  const int lr = l >> 3, cl = l & 7;
  const int fr = l & 15, q4 = l >> 4;
  const int fc = fr;

  floatx4 acc[2][4];
#pragma unroll
  for (int mi = 0; mi < 2; ++mi)
#pragma unroll
    for (int ni = 0; ni < 4; ++ni)
#pragma unroll
      for (int r = 0; r < 4; ++r) acc[mi][ni][r] = 0.0f;

  for (int k0 = 0; k0 < CDIM; k0 += 64) {
#pragma unroll
    for (int i = 0; i < 2; ++i) {
      int row = i * 32 + w * 8 + lr;
      int cg = cl ^ (row & 7);
      gl2lds16(Xb + (size_t)(bM * 64 + row) * CDIM + k0 + cg * 8,
               As + row * 64 + cl * 8);
    }
#pragma unroll
    for (int i = 0; i < 4; ++i) {
      int row = i * 32 + w * 8 + lr;
      int cg = cl ^ (row & 7);
      gl2lds16(Wqkvb + (size_t)(bN * 128 + row) * CDIM + k0 + cg * 8,
               Bs + row * 64 + cl * 8);
    }
    __syncthreads();
#pragma unroll
    for (int kk = 0; kk < 2; ++kk) {
      const int cgk = kk * 4 + q4;
      bf16x8 af[2], bfr[4];
#pragma unroll
      for (int mi = 0; mi < 2; ++mi) {
        int row = wm * 32 + mi * 16 + fr;
        af[mi] = *(const bf16x8*)(As + row * 64 + (cgk ^ (row & 7)) * 8);
      }
#pragma unroll
      for (int ni = 0; ni < 4; ++ni) {
        int row = wn * 64 + ni * 16 + fr;
        bfr[ni] = *(const bf16x8*)(Bs + row * 64 + (cgk ^ (row & 7)) * 8);
      }
#pragma unroll
      for (int mi = 0; mi < 2; ++mi)
#pragma unroll
        for (int ni = 0; ni < 4; ++ni)
          acc[mi][ni] = MFMA_16x16x32(af[mi], bfr[ni], acc[mi][ni]);
    }
    __syncthreads();
  }

  const int seg = bN >> 3;  // 0=Q, 1=K, 2=V (uniform per block)
  const float QSCALE = 0.125f * 1.44269504089f;
  const float* bp = (seg == 0) ? bq : (seg == 1) ? bk : bv;

#pragma unroll
  for (int ni = 0; ni < 4; ++ni) {
    int jl = wn * 64 + ni * 16 + fc;
    float bias = bp[(bN * 128 + jl) & 1023];
#pragma unroll
    for (int mi = 0; mi < 2; ++mi)
#pragma unroll
      for (int r = 0; r < 4; ++r) {
        int ttl = wm * 32 + mi * 16 + q4 * 4 + r;
        float val = acc[mi][ni][r] + bias;
        if (seg == 0) val *= QSCALE;
        int addr = (seg == 2) ? jl * 72 + ttl : ttl * 136 + jl;
        Cs[addr] = (bf16)val;
      }
  }
  __syncthreads();

  if (seg < 2) {
    bf16* basep = (seg == 0) ? Qb : Kb;
    const int chunk = tid & 15;
    const int rb = (tid >> 4) * 4;
#pragma unroll
    for (int u = 0; u < 4; ++u) {
      int maj = rb + u;  // tt_local
      bf16x8 vdat = *(const bf16x8*)(Cs + maj * 136 + chunk * 8);
      int n = bM * 64 + maj;
      int b = n >> 11, tt = n & 2047;
      int j = bN * 128 + chunk * 8;
      int h = (j >> 6) & 15, d = j & 63;
      *(bf16x8*)(basep + (((size_t)(b * 16 + h) * T_SEQ + tt) << 6) + d) = vdat;
    }
  } else {
    const int chunk = tid & 7;
    const int rb = (tid >> 3) * 4;
#pragma unroll
    for (int u = 0; u < 4; ++u) {
      int maj = rb + u;  // j_local
      bf16x8 vdat = *(const bf16x8*)(Cs + maj * 72 + chunk * 8);
      int j = bN * 128 + maj;
      int h = (j >> 6) & 15, d = j & 63;
      int n0 = bM * 64 + chunk * 8;
      int b = n0 >> 11, tt0 = n0 & 2047;
      *(bf16x8*)(Vtb + ((size_t)(b * 16 + h) * 64 + d) * T_SEQ + tt0) = vdat;
    }
  }
}

// ---------------------------------------------------------------------------
// Kernel 3: causal flash attention, split-KV (parity), double-buffered LDS,
// one barrier per iteration. Grid (32 bh, 64): y -> qt = 31-(y>>1), half=y&1.
// Block = 4 waves; wave w owns Q rows [qt*64+w*16, +16). Partial O,l via
// fp32 atomicAdd (no-max exp2 softmax => partials are exactly additive).
__global__ __launch_bounds__(256) void flash_attn(
    const bf16* __restrict__ Qb, const bf16* __restrict__ Kb,
    const bf16* __restrict__ Vtb, float* __restrict__ Oacc,
    float* __restrict__ Lacc) {
  __shared__ __align__(16) bf16 Ks[2 * 64 * 64];
  __shared__ __align__(16) bf16 Vs[2 * 64 * 64];
  __shared__ __align__(16) bf16 Ps[4][16 * 72];

  const int bh = blockIdx.x;               // b*16+h
  const int qt = 31 - (blockIdx.y >> 1);   // longest first
  const int half = blockIdx.y & 1;         // kv parity
  const int n = (qt >= half) ? ((qt - half) >> 1) + 1 : 0;
  if (n == 0) return;  // uniform per block

  const int b = bh >> 4, h = bh & 15;
  const int tid = threadIdx.x;
  const int w = tid >> 6, l = tid & 63;
  const int fc = l & 15, q4 = l >> 4;
  const int lr = l >> 3, cl = l & 7;

  const bf16* Qg = Qb + (size_t)bh * T_SEQ * 64;
  const bf16* Kg = Kb + (size_t)bh * T_SEQ * 64;
  const bf16* Vg = Vtb + (size_t)bh * 64 * T_SEQ;

  // Q A-frags, loaded once (already scaled by (1/8)*log2e)
  const int qrow = qt * 64 + w * 16 + fc;
  bf16x8 qf[2];
  qf[0] = *(const bf16x8*)(Qg + (size_t)qrow * 64 + q4 * 8);
  qf[1] = *(const bf16x8*)(Qg + (size_t)qrow * 64 + 32 + q4 * 8);

  bf16x8 ones;
#pragma unroll
  for (int i = 0; i < 8; ++i) ones[i] = (bf16)1.0f;

  floatx4 o[4];
  floatx4 lacc;
#pragma unroll
  for (int ds = 0; ds < 4; ++ds)
#pragma unroll
    for (int r = 0; r < 4; ++r) o[ds][r] = 0.0f;
#pragma unroll
  for (int r = 0; r < 4; ++r) lacc[r] = 0.0f;

  auto stage = [&](int pb, int kvb) {
#pragma unroll
    for (int i2 = 0; i2 < 2; ++i2) {
      int row = i2 * 32 + w * 8 + lr;
      int cg = cl ^ (row & 7);
      gl2lds16(Kg + (size_t)(kvb + row) * 64 + cg * 8,
               Ks + pb * 4096 + row * 64 + cl * 8);
      gl2lds16(Vg + (size_t)row * T_SEQ + kvb + cg * 8,
               Vs + pb * 4096 + row * 64 + cl * 8);
    }
  };

  stage(0, half * 64);
  int p = 0;
  for (int i = 0; i < n; ++i) {
    __syncthreads();  // compiler's vmcnt(0) drain covers loads issued last iter
    if (i + 1 < n) stage(p ^ 1, (half + 2 * (i + 1)) * 64);
    const int kv = half + 2 * i;
    const bf16* Ksp = Ks + p * 4096;
    const bf16* Vsp = Vs + p * 4096;

    // S = Q K^T  (16 q-rows x 64 kv-cols per wave), log2 domain
    floatx4 s[4];
#pragma unroll
    for (int ni = 0; ni < 4; ++ni)
#pragma unroll
      for (int r = 0; r < 4; ++r) s[ni][r] = 0.0f;
#pragma unroll
    for (int kk = 0; kk < 2; ++kk) {
      const int cgk = kk * 4 + q4;
#pragma unroll
      for (int ni = 0; ni < 4; ++ni) {
        int row = ni * 16 + fc;
        bf16x8 kf = *(const bf16x8*)(Ksp + row * 64 + (cgk ^ (row & 7)) * 8);
        s[ni] = MFMA_16x16x32(qf[kk], kf, s[ni]);
      }
    }

    // P = exp2(S); masked entries 0. C-layout -> Ps for A-frag re-read.
    if (kv == qt) {
      int qc = w * 16 + q4 * 4;
#pragma unroll
      for (int ni = 0; ni < 4; ++ni)
#pragma unroll
        for (int r = 0; r < 4; ++r) {
          int kc = ni * 16 + fc;
          float pv = (kc > qc + r) ? 0.0f : __builtin_amdgcn_exp2f(s[ni][r]);
          Ps[w][(q4 * 4 + r) * 72 + ni * 16 + fc] = (bf16)pv;
        }
    } else {
#pragma unroll
      for (int ni = 0; ni < 4; ++ni)
#pragma unroll
        for (int r = 0; r < 4; ++r)
          Ps[w][(q4 * 4 + r) * 72 + ni * 16 + fc] =
              (bf16)__builtin_amdgcn_exp2f(s[ni][r]);
    }

    // O += P V ; l += P 1
#pragma unroll
    for (int kk = 0; kk < 2; ++kk) {
      bf16x8 pf = *(const bf16x8*)(&Ps[w][fc * 72 + kk * 32 + q4 * 8]);
      const int cgk = kk * 4 + q4;
#pragma unroll
      for (int ds = 0; ds < 4; ++ds) {
        int row = ds * 16 + fc;
        bf16x8 vf = *(const bf16x8*)(Vsp + row * 64 + (cgk ^ (row & 7)) * 8);
        o[ds] = MFMA_16x16x32(pf, vf, o[ds]);
      }
      lacc = MFMA_16x16x32(pf, ones, lacc);
    }
    p ^= 1;
  }

  // epilogue: partial O,l -> fp32 accumulators (exactly 2 contributors/cell)
#pragma unroll
  for (int ds = 0; ds < 4; ++ds)
#pragma unroll
    for (int r = 0; r < 4; ++r) {
      int tt = qt * 64 + w * 16 + q4 * 4 + r;
      atomicAdd(Oacc + (((size_t)(b * T_SEQ + tt)) << 10) + h * 64 + ds * 16 + fc,
                o[ds][r]);
    }
  if (fc == 0) {
#pragma unroll
    for (int r = 0; r < 4; ++r) {
      int tt = qt * 64 + w * 16 + q4 * 4 + r;
      atomicAdd(Lacc + bh * T_SEQ + tt, lacc[r]);
    }
  }
}

// ---------------------------------------------------------------------------
// Kernel 3b: normalize O/l -> Ao bf16 [B,T,C]
__global__ __launch_bounds__(256) void normalize_kernel(
    const float* __restrict__ Oacc, const float* __restrict__ Lacc,
    bf16* __restrict__ Ao) {
  int gid = (blockIdx.x * 256 + threadIdx.x) * 4;  // 4194304 elems
  int row = gid >> 10;     // 0..4095
  int col = gid & 1023;
  int b = row >> 11, tt = row & 2047, h = col >> 6;
  float lv = Lacc[((b << 4) + h) * T_SEQ + tt];
  float inv = __builtin_amdgcn_rcpf(lv);
  float4 ov = *(const float4*)(Oacc + gid);
  bf16x4 r;
  r[0] = (bf16)(ov.x * inv); r[1] = (bf16)(ov.y * inv);
  r[2] = (bf16)(ov.z * inv); r[3] = (bf16)(ov.w * inv);
  *(bf16x4*)(Ao + gid) = r;
}

// ---------------------------------------------------------------------------
// Kernel 4: output projection, 64x64 tiles (1024 blocks -> 4/CU), fp32 result
__global__ __launch_bounds__(256) void gemm_out(
    const bf16* __restrict__ Ab, const bf16* __restrict__ Wob,
    const float* __restrict__ bo, float* __restrict__ Y) {
  __shared__ __align__(16) bf16 As[64 * 64];   // 8 KB
  __shared__ __align__(16) bf16 Bs[64 * 64];   // 8 KB
  const int bM = blockIdx.x & 63;
  const int bN = blockIdx.x >> 6;
  const int tid = threadIdx.x;
  const int w = tid >> 6, l = tid & 63;
  const int wm = w & 1, wn = w >> 1;
  const int lr = l >> 3, cl = l & 7;
  const int fr = l & 15, q4 = l >> 4;
  const int fc = fr;

  floatx4 acc[2][2];
#pragma unroll
  for (int mi = 0; mi < 2; ++mi)
#pragma unroll
    for (int ni = 0; ni < 2; ++ni)
#pragma unroll
      for (int r = 0; r < 4; ++r) acc[mi][ni][r] = 0.0f;

  for (int k0 = 0; k0 < CDIM; k0 += 64) {
#pragma unroll
    for (int i = 0; i < 2; ++i) {
      int row = i * 32 + w * 8 + lr;
      int cg = cl ^ (row & 7);
      gl2lds16(Ab + (size_t)(bM * 64 + row) * CDIM + k0 + cg * 8,
               As + row * 64 + cl * 8);
      gl2lds16(Wob + (size_t)(bN * 64 + row) * CDIM + k0 + cg * 8,
               Bs + row * 64 + cl * 8);
    }
    __syncthreads();
#pragma unroll
    for (int kk = 0; kk < 2; ++kk) {
      const int cgk = kk * 4 + q4;
      bf16x8 af[2], bfr[2];
#pragma unroll
      for (int mi = 0; mi < 2; ++mi) {
        int row = wm * 32 + mi * 16 + fr;
        af[mi] = *(const bf16x8*)(As + row * 64 + (cgk ^ (row & 7)) * 8);
      }
#pragma unroll
      for (int ni = 0; ni < 2; ++ni) {
        int row = wn * 32 + ni * 16 + fr;
        bfr[ni] = *(const bf16x8*)(Bs + row * 64 + (cgk ^ (row & 7)) * 8);
      }
#pragma unroll
      for (int mi = 0; mi < 2; ++mi)
#pragma unroll
        for (int ni = 0; ni < 2; ++ni)
          acc[mi][ni] = MFMA_16x16x32(af[mi], bfr[ni], acc[mi][ni]);
    }
    __syncthreads();
  }

#pragma unroll
  for (int ni = 0; ni < 2; ++ni) {
    int j = bN * 64 + wn * 32 + ni * 16 + fc;
    float bias = bo[j];
#pragma unroll
    for (int mi = 0; mi < 2; ++mi)
#pragma unroll
      for (int r = 0; r < 4; ++r) {
        int n = bM * 64 + wm * 32 + mi * 16 + q4 * 4 + r;
        Y[(size_t)n * CDIM + j] = acc[mi][ni][r] + bias;
      }
  }
}

// ---------------------------------------------------------------------------
extern "C" void kernel_launch(void* const* d_in, const int* in_sizes, int n_in,
                              void* d_out, int out_size, void* d_ws, size_t ws_size,
                              hipStream_t stream) {
  const float* x  = (const float*)d_in[0];
  const float* Wq = (const float*)d_in[1];
  const float* bq = (const float*)d_in[2];
  const float* Wk = (const float*)d_in[3];
  const float* bk = (const float*)d_in[4];
  const float* Wv = (const float*)d_in[5];
  const float* bv = (const float*)d_in[6];
  const float* Wo = (const float*)d_in[7];
  const float* bo = (const float*)d_in[8];
  float* Y = (float*)d_out;

  char* ws = (char*)d_ws;
  const size_t MB = 1024 * 1024;
  bf16*  Xb    = (bf16*)(ws + 0);         //  8 MB  [4096,1024]
  bf16*  Wqkvb = (bf16*)(ws + 8 * MB);    //  6 MB  [3072,1024]
  bf16*  Wob   = (bf16*)(ws + 14 * MB);   //  2 MB  [1024,1024]
  bf16*  Qb    = (bf16*)(ws + 16 * MB);   //  8 MB  [B,H,T,D] (log2 domain)
  bf16*  Kb    = (bf16*)(ws + 24 * MB);   //  8 MB  [B,H,T,D]
  bf16*  Vtb   = (bf16*)(ws + 32 * MB);   //  8 MB  [B,H,D,T]
  float* Oacc  = (float*)(ws + 40 * MB);  // 16 MB  [B,T,C] fp32 accum
  float* Lacc  = (float*)(ws + 56 * MB);  // .25 MB [B*H,T] fp32 accum
  bf16*  Ao    = Xb;                      // reuse: Xb dead after gemm_qkv

  // 8388608 convert elems + 4259840 zero elems = 12648448 -> 12352 blocks
  convert_kernel<<<12352, 256, 0, stream>>>(x, Wq, Wk, Wv, Wo, Xb, Wqkvb, Wob,
                                            Oacc, Lacc);
  gemm_qkv<<<64 * 24, 256, 0, stream>>>(Xb, Wqkvb, bq, bk, bv, Qb, Kb, Vtb);
  flash_attn<<<dim3(32, 64), 256, 0, stream>>>(Qb, Kb, Vtb, Oacc, Lacc);
  normalize_kernel<<<4096, 256, 0, stream>>>(Oacc, Lacc, Ao);
  gemm_out<<<64 * 16, 256, 0, stream>>>(Ao, Wob, bo, Y);
}

// Round 7
// 184.943 us; speedup vs baseline: 1.0648x; 1.0648x over previous
//
#include <hip/hip_runtime.h>
#include <hip/hip_bf16.h>
#include <stdint.h>
#include <stddef.h>

// DecoderAttention: B=2,T=2048,C=1024,H=16,D=64, causal, p=0.0
// R7: R6 post-mortem — split-KV atomics added 26 MB of RMW HBM traffic and
//     regressed; reverted. This round isolates the OTHER R6 change: flash
//     keeps R5's structure (full kv-range per block, register epilogue,
//     direct bf16 store) and adds ONLY double-buffered K/V LDS with a single
//     barrier per iteration (prefetch kv+1 issued right after the barrier,
//     lands during compute of kv; same barrier protects buffer reuse).

typedef __bf16 bf16;
typedef __attribute__((ext_vector_type(8))) __bf16 bf16x8;
typedef __attribute__((ext_vector_type(4))) __bf16 bf16x4;
typedef __attribute__((ext_vector_type(4))) float floatx4;

#define MFMA_16x16x32(A, B, C) __builtin_amdgcn_mfma_f32_16x16x32_bf16(A, B, C, 0, 0, 0)

static constexpr int T_SEQ = 2048;
static constexpr int CDIM  = 1024;

// async 16B global->LDS. LDS dest MUST be wave-uniform-base + lane*16.
__device__ __forceinline__ void gl2lds16(const bf16* g, bf16* l) {
  __builtin_amdgcn_global_load_lds(
      (const __attribute__((address_space(1))) uint32_t*)g,
      (__attribute__((address_space(3))) uint32_t*)l, 16, 0, 0);
}

// ---------------------------------------------------------------------------
// fp32 -> bf16 conversion / packing.
__global__ __launch_bounds__(256) void convert_kernel(
    const float* __restrict__ x, const float* __restrict__ Wq,
    const float* __restrict__ Wk, const float* __restrict__ Wv,
    const float* __restrict__ Wo,
    bf16* __restrict__ Xb, bf16* __restrict__ Wqkvb, bf16* __restrict__ Wob) {
  size_t i = ((size_t)blockIdx.x * 256 + threadIdx.x) * 4;  // 8388608 total elems
  const float* src;
  bf16* dst;
  size_t off;
  if (i < 4194304) {
    src = x; dst = Xb; off = i;
  } else {
    size_t r = i - 4194304;
    int wsel = (int)(r >> 20);
    off = r & 1048575;
    src = (wsel == 0) ? Wq : (wsel == 1) ? Wk : (wsel == 2) ? Wv : Wo;
    dst = (wsel < 3) ? (Wqkvb + ((size_t)wsel << 20)) : Wob;
  }
  float4 v = *(const float4*)(src + off);
  bf16x4 o;
  o[0] = (bf16)v.x; o[1] = (bf16)v.y; o[2] = (bf16)v.z; o[3] = (bf16)v.w;
  *(bf16x4*)(dst + off) = o;
}

// ---------------------------------------------------------------------------
// Kernel 2: fused QKV projection, 64x128 tiles, coalesced epilogue via LDS.
// Q pre-scaled by (1/8)*log2(e); V stored transposed [B,H,D,T].
__global__ __launch_bounds__(256) void gemm_qkv(
    const bf16* __restrict__ Xb, const bf16* __restrict__ Wqkvb,
    const float* __restrict__ bq, const float* __restrict__ bk,
    const float* __restrict__ bv,
    bf16* __restrict__ Qb, bf16* __restrict__ Kb, bf16* __restrict__ Vtb) {
  __shared__ __align__(16) bf16 smem[12288];  // 24 KB: As(4096)+Bs(8192) / Cs
  bf16* As = smem;          // 64 x 64
  bf16* Bs = smem + 4096;   // 128 x 64
  bf16* Cs = smem;          // overlay after final barrier

  const int bM = blockIdx.x & 63;   // 64 M-tiles of 64 rows (4096)
  const int bN = blockIdx.x >> 6;   // 24 N-tiles of 128 cols (3072)
  const int tid = threadIdx.x;
  const int w = tid >> 6, l = tid & 63;
  const int wm = w & 1, wn = w >> 1;   // wave tile: 32 rows x 64 cols
  const int lr = l >> 3, cl = l & 7;
  const int fr = l & 15, q4 = l >> 4;
  const int fc = fr;

  floatx4 acc[2][4];
#pragma unroll
  for (int mi = 0; mi < 2; ++mi)
#pragma unroll
    for (int ni = 0; ni < 4; ++ni)
#pragma unroll
      for (int r = 0; r < 4; ++r) acc[mi][ni][r] = 0.0f;

  for (int k0 = 0; k0 < CDIM; k0 += 64) {
#pragma unroll
    for (int i = 0; i < 2; ++i) {
      int row = i * 32 + w * 8 + lr;
      int cg = cl ^ (row & 7);
      gl2lds16(Xb + (size_t)(bM * 64 + row) * CDIM + k0 + cg * 8,
               As + row * 64 + cl * 8);
    }
#pragma unroll
    for (int i = 0; i < 4; ++i) {
      int row = i * 32 + w * 8 + lr;
      int cg = cl ^ (row & 7);
      gl2lds16(Wqkvb + (size_t)(bN * 128 + row) * CDIM + k0 + cg * 8,
               Bs + row * 64 + cl * 8);
    }
    __syncthreads();
#pragma unroll
    for (int kk = 0; kk < 2; ++kk) {
      const int cgk = kk * 4 + q4;
      bf16x8 af[2], bfr[4];
#pragma unroll
      for (int mi = 0; mi < 2; ++mi) {
        int row = wm * 32 + mi * 16 + fr;
        af[mi] = *(const bf16x8*)(As + row * 64 + (cgk ^ (row & 7)) * 8);
      }
#pragma unroll
      for (int ni = 0; ni < 4; ++ni) {
        int row = wn * 64 + ni * 16 + fr;
        bfr[ni] = *(const bf16x8*)(Bs + row * 64 + (cgk ^ (row & 7)) * 8);
      }
#pragma unroll
      for (int mi = 0; mi < 2; ++mi)
#pragma unroll
        for (int ni = 0; ni < 4; ++ni)
          acc[mi][ni] = MFMA_16x16x32(af[mi], bfr[ni], acc[mi][ni]);
    }
    __syncthreads();
  }

  const int seg = bN >> 3;  // 0=Q, 1=K, 2=V (uniform per block)
  const float QSCALE = 0.125f * 1.44269504089f;
  const float* bp = (seg == 0) ? bq : (seg == 1) ? bk : bv;

#pragma unroll
  for (int ni = 0; ni < 4; ++ni) {
    int jl = wn * 64 + ni * 16 + fc;
    float bias = bp[(bN * 128 + jl) & 1023];
#pragma unroll
    for (int mi = 0; mi < 2; ++mi)
#pragma unroll
      for (int r = 0; r < 4; ++r) {
        int ttl = wm * 32 + mi * 16 + q4 * 4 + r;
        float val = acc[mi][ni][r] + bias;
        if (seg == 0) val *= QSCALE;
        int addr = (seg == 2) ? jl * 72 + ttl : ttl * 136 + jl;
        Cs[addr] = (bf16)val;
      }
  }
  __syncthreads();

  if (seg < 2) {
    bf16* basep = (seg == 0) ? Qb : Kb;
    const int chunk = tid & 15;
    const int rb = (tid >> 4) * 4;
#pragma unroll
    for (int u = 0; u < 4; ++u) {
      int maj = rb + u;  // tt_local
      bf16x8 vdat = *(const bf16x8*)(Cs + maj * 136 + chunk * 8);
      int n = bM * 64 + maj;
      int b = n >> 11, tt = n & 2047;
      int j = bN * 128 + chunk * 8;
      int h = (j >> 6) & 15, d = j & 63;
      *(bf16x8*)(basep + (((size_t)(b * 16 + h) * T_SEQ + tt) << 6) + d) = vdat;
    }
  } else {
    const int chunk = tid & 7;
    const int rb = (tid >> 3) * 4;
#pragma unroll
    for (int u = 0; u < 4; ++u) {
      int maj = rb + u;  // j_local
      bf16x8 vdat = *(const bf16x8*)(Cs + maj * 72 + chunk * 8);
      int j = bN * 128 + maj;
      int h = (j >> 6) & 15, d = j & 63;
      int n0 = bM * 64 + chunk * 8;
      int b = n0 >> 11, tt0 = n0 & 2047;
      *(bf16x8*)(Vtb + ((size_t)(b * 16 + h) * 64 + d) * T_SEQ + tt0) = vdat;
    }
  }
}

// ---------------------------------------------------------------------------
// Kernel 3: causal flash attention, no-max exp2 softmax, Q-tile = 64 rows,
// double-buffered K/V LDS, ONE barrier per iteration.
// Grid (B*H, T/64), longest-first: qt = 31 - blockIdx.y.
__global__ __launch_bounds__(256) void flash_attn(
    const bf16* __restrict__ Qb, const bf16* __restrict__ Kb,
    const bf16* __restrict__ Vtb, bf16* __restrict__ Ao) {
  __shared__ __align__(16) bf16 Ks[2 * 64 * 64];  // 16 KB
  __shared__ __align__(16) bf16 Vs[2 * 64 * 64];  // 16 KB
  __shared__ __align__(16) bf16 Ps[4][16 * 72];   //  9 KB

  const int bh = blockIdx.x;            // 0..31 = b*16+h
  const int qt = 31 - blockIdx.y;       // longest blocks dispatch first
  const int b = bh >> 4, h = bh & 15;
  const int tid = threadIdx.x;
  const int w = tid >> 6, l = tid & 63;
  const int fc = l & 15, q4 = l >> 4;
  const int lr = l >> 3, cl = l & 7;

  const bf16* Qg = Qb + (size_t)bh * T_SEQ * 64;
  const bf16* Kg = Kb + (size_t)bh * T_SEQ * 64;
  const bf16* Vg = Vtb + (size_t)bh * 64 * T_SEQ;

  // Q A-frags, loaded once (already scaled by (1/8)*log2e)
  const int qrow = qt * 64 + w * 16 + fc;
  bf16x8 qf[2];
  qf[0] = *(const bf16x8*)(Qg + (size_t)qrow * 64 + q4 * 8);
  qf[1] = *(const bf16x8*)(Qg + (size_t)qrow * 64 + 32 + q4 * 8);

  bf16x8 ones;
#pragma unroll
  for (int i = 0; i < 8; ++i) ones[i] = (bf16)1.0f;

  floatx4 o[4];
  floatx4 lacc;  // row-sum of P via MFMA ones-trick
#pragma unroll
  for (int ds = 0; ds < 4; ++ds)
#pragma unroll
    for (int r = 0; r < 4; ++r) o[ds][r] = 0.0f;
#pragma unroll
  for (int r = 0; r < 4; ++r) lacc[r] = 0.0f;

  auto stage = [&](int pb, int kvb) {
#pragma unroll
    for (int i2 = 0; i2 < 2; ++i2) {
      int row = i2 * 32 + w * 8 + lr;
      int cg = cl ^ (row & 7);
      gl2lds16(Kg + (size_t)(kvb + row) * 64 + cg * 8,
               Ks + pb * 4096 + row * 64 + cl * 8);
      gl2lds16(Vg + (size_t)row * T_SEQ + kvb + cg * 8,
               Vs + pb * 4096 + row * 64 + cl * 8);
    }
  };

  stage(0, 0);
  int p = 0;
  for (int kv = 0; kv <= qt; ++kv) {
    // ONE barrier: compiler's vmcnt(0) drain covers the prefetch issued last
    // iter (it had the whole compute phase to fly); barrier also ensures all
    // waves finished reading the buffer the next prefetch will overwrite.
    __syncthreads();
    if (kv < qt) stage(p ^ 1, (kv + 1) * 64);
    const bf16* Ksp = Ks + p * 4096;
    const bf16* Vsp = Vs + p * 4096;

    // S = Q K^T  (16 q-rows x 64 kv-cols per wave), log2 domain
    floatx4 s[4];
#pragma unroll
    for (int ni = 0; ni < 4; ++ni)
#pragma unroll
      for (int r = 0; r < 4; ++r) s[ni][r] = 0.0f;
#pragma unroll
    for (int kk = 0; kk < 2; ++kk) {
      const int cgk = kk * 4 + q4;
#pragma unroll
      for (int ni = 0; ni < 4; ++ni) {
        int row = ni * 16 + fc;
        bf16x8 kf = *(const bf16x8*)(Ksp + row * 64 + (cgk ^ (row & 7)) * 8);
        s[ni] = MFMA_16x16x32(qf[kk], kf, s[ni]);
      }
    }

    // P = exp2(S) (no max: logits O(10), fp32-safe, shift-invariance exact);
    // masked entries p = 0. C-layout -> Ps for A-frag re-read (per-wave, no
    // cross-wave barrier needed).
    if (kv == qt) {
      int qc = w * 16 + q4 * 4;
#pragma unroll
      for (int ni = 0; ni < 4; ++ni)
#pragma unroll
        for (int r = 0; r < 4; ++r) {
          int kc = ni * 16 + fc;
          float pv = (kc > qc + r) ? 0.0f : __builtin_amdgcn_exp2f(s[ni][r]);
          Ps[w][(q4 * 4 + r) * 72 + ni * 16 + fc] = (bf16)pv;
        }
    } else {
#pragma unroll
      for (int ni = 0; ni < 4; ++ni)
#pragma unroll
        for (int r = 0; r < 4; ++r)
          Ps[w][(q4 * 4 + r) * 72 + ni * 16 + fc] =
              (bf16)__builtin_amdgcn_exp2f(s[ni][r]);
    }

    // O += P V ; l += P 1  (row-sum on the MFMA pipe)
#pragma unroll
    for (int kk = 0; kk < 2; ++kk) {
      bf16x8 pf = *(const bf16x8*)(&Ps[w][fc * 72 + kk * 32 + q4 * 8]);
      const int cgk = kk * 4 + q4;
#pragma unroll
      for (int ds = 0; ds < 4; ++ds) {
        int row = ds * 16 + fc;
        bf16x8 vf = *(const bf16x8*)(Vsp + row * 64 + (cgk ^ (row & 7)) * 8);
        o[ds] = MFMA_16x16x32(pf, vf, o[ds]);
      }
      lacc = MFMA_16x16x32(pf, ones, lacc);
    }
    p ^= 1;
  }

  // epilogue: O/l -> AttnOut[B,T,C] bf16
  float inv[4];
#pragma unroll
  for (int r = 0; r < 4; ++r) inv[r] = __builtin_amdgcn_rcpf(lacc[r]);
#pragma unroll
  for (int ds = 0; ds < 4; ++ds)
#pragma unroll
    for (int r = 0; r < 4; ++r) {
      int tt = qt * 64 + w * 16 + q4 * 4 + r;
      int col = h * 64 + ds * 16 + fc;
      Ao[((size_t)(b * T_SEQ + tt) << 10) + col] = (bf16)(o[ds][r] * inv[r]);
    }
}

// ---------------------------------------------------------------------------
// Kernel 4: output projection, 64x64 tiles (1024 blocks -> 4/CU), fp32 result
__global__ __launch_bounds__(256) void gemm_out(
    const bf16* __restrict__ Ab, const bf16* __restrict__ Wob,
    const float* __restrict__ bo, float* __restrict__ Y) {
  __shared__ __align__(16) bf16 As[64 * 64];   // 8 KB
  __shared__ __align__(16) bf16 Bs[64 * 64];   // 8 KB
  const int bM = blockIdx.x & 63;
  const int bN = blockIdx.x >> 6;
  const int tid = threadIdx.x;
  const int w = tid >> 6, l = tid & 63;
  const int wm = w & 1, wn = w >> 1;
  const int lr = l >> 3, cl = l & 7;
  const int fr = l & 15, q4 = l >> 4;
  const int fc = fr;

  floatx4 acc[2][2];
#pragma unroll
  for (int mi = 0; mi < 2; ++mi)
#pragma unroll
    for (int ni = 0; ni < 2; ++ni)
#pragma unroll
      for (int r = 0; r < 4; ++r) acc[mi][ni][r] = 0.0f;

  for (int k0 = 0; k0 < CDIM; k0 += 64) {
#pragma unroll
    for (int i = 0; i < 2; ++i) {
      int row = i * 32 + w * 8 + lr;
      int cg = cl ^ (row & 7);
      gl2lds16(Ab + (size_t)(bM * 64 + row) * CDIM + k0 + cg * 8,
               As + row * 64 + cl * 8);
      gl2lds16(Wob + (size_t)(bN * 64 + row) * CDIM + k0 + cg * 8,
               Bs + row * 64 + cl * 8);
    }
    __syncthreads();
#pragma unroll
    for (int kk = 0; kk < 2; ++kk) {
      const int cgk = kk * 4 + q4;
      bf16x8 af[2], bfr[2];
#pragma unroll
      for (int mi = 0; mi < 2; ++mi) {
        int row = wm * 32 + mi * 16 + fr;
        af[mi] = *(const bf16x8*)(As + row * 64 + (cgk ^ (row & 7)) * 8);
      }
#pragma unroll
      for (int ni = 0; ni < 2; ++ni) {
        int row = wn * 32 + ni * 16 + fr;
        bfr[ni] = *(const bf16x8*)(Bs + row * 64 + (cgk ^ (row & 7)) * 8);
      }
#pragma unroll
      for (int mi = 0; mi < 2; ++mi)
#pragma unroll
        for (int ni = 0; ni < 2; ++ni)
          acc[mi][ni] = MFMA_16x16x32(af[mi], bfr[ni], acc[mi][ni]);
    }
    __syncthreads();
  }

#pragma unroll
  for (int ni = 0; ni < 2; ++ni) {
    int j = bN * 64 + wn * 32 + ni * 16 + fc;
    float bias = bo[j];
#pragma unroll
    for (int mi = 0; mi < 2; ++mi)
#pragma unroll
      for (int r = 0; r < 4; ++r) {
        int n = bM * 64 + wm * 32 + mi * 16 + q4 * 4 + r;
        Y[(size_t)n * CDIM + j] = acc[mi][ni][r] + bias;
      }
  }
}

// ---------------------------------------------------------------------------
extern "C" void kernel_launch(void* const* d_in, const int* in_sizes, int n_in,
                              void* d_out, int out_size, void* d_ws, size_t ws_size,
                              hipStream_t stream) {
  const float* x  = (const float*)d_in[0];
  const float* Wq = (const float*)d_in[1];
  const float* bq = (const float*)d_in[2];
  const float* Wk = (const float*)d_in[3];
  const float* bk = (const float*)d_in[4];
  const float* Wv = (const float*)d_in[5];
  const float* bv = (const float*)d_in[6];
  const float* Wo = (const float*)d_in[7];
  const float* bo = (const float*)d_in[8];
  float* Y = (float*)d_out;

  char* ws = (char*)d_ws;
  const size_t MB = 1024 * 1024;
  bf16* Xb    = (bf16*)(ws + 0);        //  8 MB  [4096,1024]
  bf16* Wqkvb = (bf16*)(ws + 8 * MB);   //  6 MB  [3072,1024]
  bf16* Wob   = (bf16*)(ws + 14 * MB);  //  2 MB  [1024,1024]
  bf16* Qb    = (bf16*)(ws + 16 * MB);  //  8 MB  [B,H,T,D] (log2 domain)
  bf16* Kb    = (bf16*)(ws + 24 * MB);  //  8 MB  [B,H,T,D]
  bf16* Vtb   = (bf16*)(ws + 32 * MB);  //  8 MB  [B,H,D,T]
  bf16* Ao    = Xb;                     //  reuse: Xb dead after gemm_qkv

  convert_kernel<<<8192, 256, 0, stream>>>(x, Wq, Wk, Wv, Wo, Xb, Wqkvb, Wob);
  gemm_qkv<<<64 * 24, 256, 0, stream>>>(Xb, Wqkvb, bq, bk, bv, Qb, Kb, Vtb);
  flash_attn<<<dim3(32, 32), 256, 0, stream>>>(Qb, Kb, Vtb, Ao);
  gemm_out<<<64 * 16, 256, 0, stream>>>(Ao, Wob, bo, Y);
}

// Round 8
// 181.737 us; speedup vs baseline: 1.0836x; 1.0176x over previous
//
#include <hip/hip_runtime.h>
#include <hip/hip_bf16.h>
#include <stdint.h>
#include <stddef.h>

// DecoderAttention: B=2,T=2048,C=1024,H=16,D=64, causal, p=0.0
// R8: flash CU-load balancing. R7 showed dbuf neutral -> the wall is the
//     straggler CU: with qt=31-y and stride-256 block->CU grouping, per-CU
//     iteration totals ranged 52..80. New qt map partitions 0..31 into 8
//     quadruples {31-a, 16+a, 15-a, a} (a = y&7) each summing to 62 (+4 = 66
//     iters), so every CU gets equal work; longest blocks dispatch first.
//     flash back to R5 single-buffer (25.6 KB -> 4 blocks/CU resident).

typedef __bf16 bf16;
typedef __attribute__((ext_vector_type(8))) __bf16 bf16x8;
typedef __attribute__((ext_vector_type(4))) __bf16 bf16x4;
typedef __attribute__((ext_vector_type(4))) float floatx4;

#define MFMA_16x16x32(A, B, C) __builtin_amdgcn_mfma_f32_16x16x32_bf16(A, B, C, 0, 0, 0)

static constexpr int T_SEQ = 2048;
static constexpr int CDIM  = 1024;

// async 16B global->LDS. LDS dest MUST be wave-uniform-base + lane*16.
__device__ __forceinline__ void gl2lds16(const bf16* g, bf16* l) {
  __builtin_amdgcn_global_load_lds(
      (const __attribute__((address_space(1))) uint32_t*)g,
      (__attribute__((address_space(3))) uint32_t*)l, 16, 0, 0);
}

// ---------------------------------------------------------------------------
// fp32 -> bf16 conversion / packing.
__global__ __launch_bounds__(256) void convert_kernel(
    const float* __restrict__ x, const float* __restrict__ Wq,
    const float* __restrict__ Wk, const float* __restrict__ Wv,
    const float* __restrict__ Wo,
    bf16* __restrict__ Xb, bf16* __restrict__ Wqkvb, bf16* __restrict__ Wob) {
  size_t i = ((size_t)blockIdx.x * 256 + threadIdx.x) * 4;  // 8388608 total elems
  const float* src;
  bf16* dst;
  size_t off;
  if (i < 4194304) {
    src = x; dst = Xb; off = i;
  } else {
    size_t r = i - 4194304;
    int wsel = (int)(r >> 20);
    off = r & 1048575;
    src = (wsel == 0) ? Wq : (wsel == 1) ? Wk : (wsel == 2) ? Wv : Wo;
    dst = (wsel < 3) ? (Wqkvb + ((size_t)wsel << 20)) : Wob;
  }
  float4 v = *(const float4*)(src + off);
  bf16x4 o;
  o[0] = (bf16)v.x; o[1] = (bf16)v.y; o[2] = (bf16)v.z; o[3] = (bf16)v.w;
  *(bf16x4*)(dst + off) = o;
}

// ---------------------------------------------------------------------------
// Kernel 2: fused QKV projection, 64x128 tiles, coalesced epilogue via LDS.
// Q pre-scaled by (1/8)*log2(e); V stored transposed [B,H,D,T].
__global__ __launch_bounds__(256) void gemm_qkv(
    const bf16* __restrict__ Xb, const bf16* __restrict__ Wqkvb,
    const float* __restrict__ bq, const float* __restrict__ bk,
    const float* __restrict__ bv,
    bf16* __restrict__ Qb, bf16* __restrict__ Kb, bf16* __restrict__ Vtb) {
  __shared__ __align__(16) bf16 smem[12288];  // 24 KB: As(4096)+Bs(8192) / Cs
  bf16* As = smem;          // 64 x 64
  bf16* Bs = smem + 4096;   // 128 x 64
  bf16* Cs = smem;          // overlay after final barrier

  const int bM = blockIdx.x & 63;   // 64 M-tiles of 64 rows (4096)
  const int bN = blockIdx.x >> 6;   // 24 N-tiles of 128 cols (3072)
  const int tid = threadIdx.x;
  const int w = tid >> 6, l = tid & 63;
  const int wm = w & 1, wn = w >> 1;   // wave tile: 32 rows x 64 cols
  const int lr = l >> 3, cl = l & 7;
  const int fr = l & 15, q4 = l >> 4;
  const int fc = fr;

  floatx4 acc[2][4];
#pragma unroll
  for (int mi = 0; mi < 2; ++mi)
#pragma unroll
    for (int ni = 0; ni < 4; ++ni)
#pragma unroll
      for (int r = 0; r < 4; ++r) acc[mi][ni][r] = 0.0f;

  for (int k0 = 0; k0 < CDIM; k0 += 64) {
#pragma unroll
    for (int i = 0; i < 2; ++i) {
      int row = i * 32 + w * 8 + lr;
      int cg = cl ^ (row & 7);
      gl2lds16(Xb + (size_t)(bM * 64 + row) * CDIM + k0 + cg * 8,
               As + row * 64 + cl * 8);
    }
#pragma unroll
    for (int i = 0; i < 4; ++i) {
      int row = i * 32 + w * 8 + lr;
      int cg = cl ^ (row & 7);
      gl2lds16(Wqkvb + (size_t)(bN * 128 + row) * CDIM + k0 + cg * 8,
               Bs + row * 64 + cl * 8);
    }
    __syncthreads();
#pragma unroll
    for (int kk = 0; kk < 2; ++kk) {
      const int cgk = kk * 4 + q4;
      bf16x8 af[2], bfr[4];
#pragma unroll
      for (int mi = 0; mi < 2; ++mi) {
        int row = wm * 32 + mi * 16 + fr;
        af[mi] = *(const bf16x8*)(As + row * 64 + (cgk ^ (row & 7)) * 8);
      }
#pragma unroll
      for (int ni = 0; ni < 4; ++ni) {
        int row = wn * 64 + ni * 16 + fr;
        bfr[ni] = *(const bf16x8*)(Bs + row * 64 + (cgk ^ (row & 7)) * 8);
      }
#pragma unroll
      for (int mi = 0; mi < 2; ++mi)
#pragma unroll
        for (int ni = 0; ni < 4; ++ni)
          acc[mi][ni] = MFMA_16x16x32(af[mi], bfr[ni], acc[mi][ni]);
    }
    __syncthreads();
  }

  const int seg = bN >> 3;  // 0=Q, 1=K, 2=V (uniform per block)
  const float QSCALE = 0.125f * 1.44269504089f;
  const float* bp = (seg == 0) ? bq : (seg == 1) ? bk : bv;

#pragma unroll
  for (int ni = 0; ni < 4; ++ni) {
    int jl = wn * 64 + ni * 16 + fc;
    float bias = bp[(bN * 128 + jl) & 1023];
#pragma unroll
    for (int mi = 0; mi < 2; ++mi)
#pragma unroll
      for (int r = 0; r < 4; ++r) {
        int ttl = wm * 32 + mi * 16 + q4 * 4 + r;
        float val = acc[mi][ni][r] + bias;
        if (seg == 0) val *= QSCALE;
        int addr = (seg == 2) ? jl * 72 + ttl : ttl * 136 + jl;
        Cs[addr] = (bf16)val;
      }
  }
  __syncthreads();

  if (seg < 2) {
    bf16* basep = (seg == 0) ? Qb : Kb;
    const int chunk = tid & 15;
    const int rb = (tid >> 4) * 4;
#pragma unroll
    for (int u = 0; u < 4; ++u) {
      int maj = rb + u;  // tt_local
      bf16x8 vdat = *(const bf16x8*)(Cs + maj * 136 + chunk * 8);
      int n = bM * 64 + maj;
      int b = n >> 11, tt = n & 2047;
      int j = bN * 128 + chunk * 8;
      int h = (j >> 6) & 15, d = j & 63;
      *(bf16x8*)(basep + (((size_t)(b * 16 + h) * T_SEQ + tt) << 6) + d) = vdat;
    }
  } else {
    const int chunk = tid & 7;
    const int rb = (tid >> 3) * 4;
#pragma unroll
    for (int u = 0; u < 4; ++u) {
      int maj = rb + u;  // j_local
      bf16x8 vdat = *(const bf16x8*)(Cs + maj * 72 + chunk * 8);
      int j = bN * 128 + maj;
      int h = (j >> 6) & 15, d = j & 63;
      int n0 = bM * 64 + chunk * 8;
      int b = n0 >> 11, tt0 = n0 & 2047;
      *(bf16x8*)(Vtb + ((size_t)(b * 16 + h) * 64 + d) * T_SEQ + tt0) = vdat;
    }
  }
}

// ---------------------------------------------------------------------------
// Kernel 3: causal flash attention, no-max exp2 softmax, Q-tile = 64 rows,
// single-buffered LDS (25.6 KB -> 4 blocks/CU), balanced qt partition:
// y -> a=y&7, k=y>>3, qt = {31-a, 16+a, 15-a, a}[k]. Each CU's stride-256
// block set {a, 8+a, 16+a, 24+a} then sums to exactly 66 iterations.
__global__ __launch_bounds__(256) void flash_attn(
    const bf16* __restrict__ Qb, const bf16* __restrict__ Kb,
    const bf16* __restrict__ Vtb, bf16* __restrict__ Ao) {
  __shared__ __align__(16) bf16 Ks[64 * 64];
  __shared__ __align__(16) bf16 Vs[64 * 64];
  __shared__ __align__(16) bf16 Ps[4][16 * 72];  // +8 pad

  const int bh = blockIdx.x;            // 0..31 = b*16+h
  const int ymap = blockIdx.y;          // 0..31
  const int a = ymap & 7, kq = ymap >> 3;
  const int qt = (kq == 0) ? 31 - a : (kq == 1) ? 16 + a : (kq == 2) ? 15 - a : a;
  const int b = bh >> 4, h = bh & 15;
  const int tid = threadIdx.x;
  const int w = tid >> 6, l = tid & 63;
  const int fc = l & 15, q4 = l >> 4;
  const int lr = l >> 3, cl = l & 7;

  const bf16* Qg = Qb + (size_t)bh * T_SEQ * 64;
  const bf16* Kg = Kb + (size_t)bh * T_SEQ * 64;
  const bf16* Vg = Vtb + (size_t)bh * 64 * T_SEQ;

  // Q A-frags, loaded once (already scaled by (1/8)*log2e)
  const int qrow = qt * 64 + w * 16 + fc;
  bf16x8 qf[2];
  qf[0] = *(const bf16x8*)(Qg + (size_t)qrow * 64 + q4 * 8);
  qf[1] = *(const bf16x8*)(Qg + (size_t)qrow * 64 + 32 + q4 * 8);

  bf16x8 ones;
#pragma unroll
  for (int i = 0; i < 8; ++i) ones[i] = (bf16)1.0f;

  floatx4 o[4];
  floatx4 lacc;  // row-sum of P via MFMA ones-trick
#pragma unroll
  for (int ds = 0; ds < 4; ++ds)
#pragma unroll
    for (int r = 0; r < 4; ++r) o[ds][r] = 0.0f;
#pragma unroll
  for (int r = 0; r < 4; ++r) lacc[r] = 0.0f;

  for (int kv = 0; kv <= qt; ++kv) {
    const int kvbase = kv * 64;
#pragma unroll
    for (int i = 0; i < 2; ++i) {
      int row = i * 32 + w * 8 + lr;
      int cg = cl ^ (row & 7);
      gl2lds16(Kg + (size_t)(kvbase + row) * 64 + cg * 8, Ks + row * 64 + cl * 8);
      gl2lds16(Vg + (size_t)row * T_SEQ + kvbase + cg * 8, Vs + row * 64 + cl * 8);
    }
    __syncthreads();

    // S = Q K^T  (16 q-rows x 64 kv-cols per wave), log2 domain
    floatx4 s[4];
#pragma unroll
    for (int ni = 0; ni < 4; ++ni)
#pragma unroll
      for (int r = 0; r < 4; ++r) s[ni][r] = 0.0f;
#pragma unroll
    for (int kk = 0; kk < 2; ++kk) {
      const int cgk = kk * 4 + q4;
#pragma unroll
      for (int ni = 0; ni < 4; ++ni) {
        int row = ni * 16 + fc;
        bf16x8 kf = *(const bf16x8*)(Ks + row * 64 + (cgk ^ (row & 7)) * 8);
        s[ni] = MFMA_16x16x32(qf[kk], kf, s[ni]);
      }
    }

    // P = exp2(S) (no max: logits O(10), fp32-safe, shift-invariance exact);
    // masked entries p = 0. C-layout -> Ps for A-frag re-read.
    if (kv == qt) {
      int qc = w * 16 + q4 * 4;
#pragma unroll
      for (int ni = 0; ni < 4; ++ni)
#pragma unroll
        for (int r = 0; r < 4; ++r) {
          int kc = ni * 16 + fc;
          float pv = (kc > qc + r) ? 0.0f : __builtin_amdgcn_exp2f(s[ni][r]);
          Ps[w][(q4 * 4 + r) * 72 + ni * 16 + fc] = (bf16)pv;
        }
    } else {
#pragma unroll
      for (int ni = 0; ni < 4; ++ni)
#pragma unroll
        for (int r = 0; r < 4; ++r)
          Ps[w][(q4 * 4 + r) * 72 + ni * 16 + fc] =
              (bf16)__builtin_amdgcn_exp2f(s[ni][r]);
    }

    // O += P V ; l += P 1  (row-sum on the MFMA pipe)
#pragma unroll
    for (int kk = 0; kk < 2; ++kk) {
      bf16x8 pf = *(const bf16x8*)(&Ps[w][fc * 72 + kk * 32 + q4 * 8]);
      const int cgk = kk * 4 + q4;
#pragma unroll
      for (int ds = 0; ds < 4; ++ds) {
        int row = ds * 16 + fc;
        bf16x8 vf = *(const bf16x8*)(Vs + row * 64 + (cgk ^ (row & 7)) * 8);
        o[ds] = MFMA_16x16x32(pf, vf, o[ds]);
      }
      lacc = MFMA_16x16x32(pf, ones, lacc);
    }
    __syncthreads();
  }

  // epilogue: O/l -> AttnOut[B,T,C] bf16
  float inv[4];
#pragma unroll
  for (int r = 0; r < 4; ++r) inv[r] = __builtin_amdgcn_rcpf(lacc[r]);
#pragma unroll
  for (int ds = 0; ds < 4; ++ds)
#pragma unroll
    for (int r = 0; r < 4; ++r) {
      int tt = qt * 64 + w * 16 + q4 * 4 + r;
      int col = h * 64 + ds * 16 + fc;
      Ao[((size_t)(b * T_SEQ + tt) << 10) + col] = (bf16)(o[ds][r] * inv[r]);
    }
}

// ---------------------------------------------------------------------------
// Kernel 4: output projection, 64x64 tiles (1024 blocks -> 4/CU), fp32 result
__global__ __launch_bounds__(256) void gemm_out(
    const bf16* __restrict__ Ab, const bf16* __restrict__ Wob,
    const float* __restrict__ bo, float* __restrict__ Y) {
  __shared__ __align__(16) bf16 As[64 * 64];   // 8 KB
  __shared__ __align__(16) bf16 Bs[64 * 64];   // 8 KB
  const int bM = blockIdx.x & 63;
  const int bN = blockIdx.x >> 6;
  const int tid = threadIdx.x;
  const int w = tid >> 6, l = tid & 63;
  const int wm = w & 1, wn = w >> 1;
  const int lr = l >> 3, cl = l & 7;
  const int fr = l & 15, q4 = l >> 4;
  const int fc = fr;

  floatx4 acc[2][2];
#pragma unroll
  for (int mi = 0; mi < 2; ++mi)
#pragma unroll
    for (int ni = 0; ni < 2; ++ni)
#pragma unroll
      for (int r = 0; r < 4; ++r) acc[mi][ni][r] = 0.0f;

  for (int k0 = 0; k0 < CDIM; k0 += 64) {
#pragma unroll
    for (int i = 0; i < 2; ++i) {
      int row = i * 32 + w * 8 + lr;
      int cg = cl ^ (row & 7);
      gl2lds16(Ab + (size_t)(bM * 64 + row) * CDIM + k0 + cg * 8,
               As + row * 64 + cl * 8);
      gl2lds16(Wob + (size_t)(bN * 64 + row) * CDIM + k0 + cg * 8,
               Bs + row * 64 + cl * 8);
    }
    __syncthreads();
#pragma unroll
    for (int kk = 0; kk < 2; ++kk) {
      const int cgk = kk * 4 + q4;
      bf16x8 af[2], bfr[2];
#pragma unroll
      for (int mi = 0; mi < 2; ++mi) {
        int row = wm * 32 + mi * 16 + fr;
        af[mi] = *(const bf16x8*)(As + row * 64 + (cgk ^ (row & 7)) * 8);
      }
#pragma unroll
      for (int ni = 0; ni < 2; ++ni) {
        int row = wn * 32 + ni * 16 + fr;
        bfr[ni] = *(const bf16x8*)(Bs + row * 64 + (cgk ^ (row & 7)) * 8);
      }
#pragma unroll
      for (int mi = 0; mi < 2; ++mi)
#pragma unroll
        for (int ni = 0; ni < 2; ++ni)
          acc[mi][ni] = MFMA_16x16x32(af[mi], bfr[ni], acc[mi][ni]);
    }
    __syncthreads();
  }

#pragma unroll
  for (int ni = 0; ni < 2; ++ni) {
    int j = bN * 64 + wn * 32 + ni * 16 + fc;
    float bias = bo[j];
#pragma unroll
    for (int mi = 0; mi < 2; ++mi)
#pragma unroll
      for (int r = 0; r < 4; ++r) {
        int n = bM * 64 + wm * 32 + mi * 16 + q4 * 4 + r;
        Y[(size_t)n * CDIM + j] = acc[mi][ni][r] + bias;
      }
  }
}

// ---------------------------------------------------------------------------
extern "C" void kernel_launch(void* const* d_in, const int* in_sizes, int n_in,
                              void* d_out, int out_size, void* d_ws, size_t ws_size,
                              hipStream_t stream) {
  const float* x  = (const float*)d_in[0];
  const float* Wq = (const float*)d_in[1];
  const float* bq = (const float*)d_in[2];
  const float* Wk = (const float*)d_in[3];
  const float* bk = (const float*)d_in[4];
  const float* Wv = (const float*)d_in[5];
  const float* bv = (const float*)d_in[6];
  const float* Wo = (const float*)d_in[7];
  const float* bo = (const float*)d_in[8];
  float* Y = (float*)d_out;

  char* ws = (char*)d_ws;
  const size_t MB = 1024 * 1024;
  bf16* Xb    = (bf16*)(ws + 0);        //  8 MB  [4096,1024]
  bf16* Wqkvb = (bf16*)(ws + 8 * MB);   //  6 MB  [3072,1024]
  bf16* Wob   = (bf16*)(ws + 14 * MB);  //  2 MB  [1024,1024]
  bf16* Qb    = (bf16*)(ws + 16 * MB);  //  8 MB  [B,H,T,D] (log2 domain)
  bf16* Kb    = (bf16*)(ws + 24 * MB);  //  8 MB  [B,H,T,D]
  bf16* Vtb   = (bf16*)(ws + 32 * MB);  //  8 MB  [B,H,D,T]
  bf16* Ao    = Xb;                     //  reuse: Xb dead after gemm_qkv

  convert_kernel<<<8192, 256, 0, stream>>>(x, Wq, Wk, Wv, Wo, Xb, Wqkvb, Wob);
  gemm_qkv<<<64 * 24, 256, 0, stream>>>(Xb, Wqkvb, bq, bk, bv, Qb, Kb, Vtb);
  flash_attn<<<dim3(32, 32), 256, 0, stream>>>(Qb, Kb, Vtb, Ao);
  gemm_out<<<64 * 16, 256, 0, stream>>>(Ao, Wob, bo, Y);
}